// Round 13
// baseline (261.732 us; speedup 1.0000x reference)
//
#include <hip/hip_runtime.h>
#include <hip/hip_bf16.h>
#include <stdint.h>

#define EMBED 2048
#define NHEADS 32
#define HDIM 64
#define BATCH 2
#define SEQ 2048
#define ATT_SCALE 0.125f
#define LOG2E 1.4426950408889634f

typedef __attribute__((ext_vector_type(8))) short bf16x8;
typedef __attribute__((ext_vector_type(4))) float f32x4;
typedef __attribute__((ext_vector_type(16))) float f32x16;
typedef __attribute__((ext_vector_type(4))) unsigned short u16x4;
typedef __attribute__((ext_vector_type(2))) unsigned int u32x2;

static __device__ __forceinline__ unsigned short f2bf(float f) {
  union { float f; uint32_t u; } v; v.f = f;
  uint32_t r = v.u + 0x7fffu + ((v.u >> 16) & 1u);
  return (unsigned short)(r >> 16);
}

static __device__ __forceinline__ void gload_lds16(const unsigned short* g, unsigned short* l) {
  __builtin_amdgcn_global_load_lds(
      (const __attribute__((address_space(1))) unsigned int*)g,
      (__attribute__((address_space(3))) unsigned int*)l, 16, 0, 0);
}

// ---------------- fp32 -> bf16 cast, all 5 tensors fused ----------------
__global__ void cvt_all(const float* __restrict__ h,
                        const float* __restrict__ Wq, const float* __restrict__ Wk,
                        const float* __restrict__ Wv, const float* __restrict__ Wo,
                        unsigned short* __restrict__ out) {
  const int n4 = 6291456;
  int idx = blockIdx.x * blockDim.x + threadIdx.x;
  int stride = gridDim.x * blockDim.x;
  for (int i = idx; i < n4; i += stride) {
    const float* src; int off;
    if (i < 2097152)      { src = h;  off = i; }
    else if (i < 3145728) { src = Wq; off = i - 2097152; }
    else if (i < 4194304) { src = Wk; off = i - 3145728; }
    else if (i < 5242880) { src = Wv; off = i - 4194304; }
    else                  { src = Wo; off = i - 5242880; }
    float4 v = ((const float4*)src)[off];
    u16x4 o;
    o.x = f2bf(v.x); o.y = f2bf(v.y); o.z = f2bf(v.z); o.w = f2bf(v.w);
    ((u16x4*)out)[i] = o;
  }
}

// ---------------- 8-phase pipelined GEMM (R6 measured-best, byte-identical) ----------------
// BM=256, BN=128, BK=64, 512 threads = 8 waves (4M x 2N), wave tile 64x64.
// MODE 0: QKV fused epilogue (bf16 scatter); MODE 1: fp32 row-major + bias.
template<int MODE, int NBJ>
__global__ __launch_bounds__(512, 2)
void gemm8(const unsigned short* __restrict__ A,
           const unsigned short* __restrict__ W,
           const float* __restrict__ b0, const float* __restrict__ b1,
           const float* __restrict__ b2,
           unsigned short* __restrict__ o0, unsigned short* __restrict__ o1,
           unsigned short* __restrict__ o2,
           float* __restrict__ fo, float qscale) {
  __shared__ unsigned short lds[2][24576];   // per buf: A [256][64] @0, B [128][64] @16384
  const int tid = threadIdx.x;
  const int w = tid >> 6, l = tid & 63;
  const int wm = w >> 1, wn = w & 1;
  const int r16 = l & 15, g = l >> 4;
  // R6 XCD swizzle (measured best): each XCD gets a contiguous swz chunk
  const int nblk = 16 * NBJ;
  const int swz = (blockIdx.x & 7) * (nblk >> 3) + (blockIdx.x >> 3);
  const int bi = swz / NBJ, bj = swz % NBJ;
  const int arow0 = bi * 256, bcol0 = bj * 128;

  f32x4 acc[4][4];
#pragma unroll
  for (int i = 0; i < 4; ++i)
#pragma unroll
    for (int j = 0; j < 4; ++j) acc[i][j] = (f32x4){0.f, 0.f, 0.f, 0.f};

  const int lrow = l >> 3;               // 0..7 within a wave's 8-row chunk
  const int gcu = ((l & 7) ^ lrow) * 8;  // pre-swizzled global column (elements)

  auto stageA = [&](int buf, int t, int mq, int call) {
    const int m = call * 8 + w;
    const int row0 = mq * 32 + (m >> 2) * 64 + (m & 3) * 8;
    gload_lds16(A + (size_t)(arow0 + row0 + lrow) * 2048 + t * 64 + gcu,
                &lds[buf][row0 * 64]);
  };
  auto stageB = [&](int buf, int t, int nq) {
    const int row0 = nq * 32 + (w >> 2) * 64 + (w & 3) * 8;
    gload_lds16(W + (size_t)(bcol0 + row0 + lrow) * 2048 + t * 64 + gcu,
                &lds[buf][16384 + row0 * 64]);
  };
  auto ldA = [&](int buf, int mf, int ks) -> bf16x8 {
    const int row = wm * 64 + mf * 16 + r16;
    const int u = (ks * 4 + g) ^ (r16 & 7);
    return *(const bf16x8*)&lds[buf][row * 64 + u * 8];
  };
  auto ldB = [&](int buf, int nf, int ks) -> bf16x8 {
    const int row = wn * 64 + nf * 16 + r16;
    const int u = (ks * 4 + g) ^ (r16 & 7);
    return *(const bf16x8*)&lds[buf][16384 + row * 64 + u * 8];
  };

  // prologue: tile 0 full -> buf0 (6 calls, oldest), tile 1 early chunks -> buf1 (3 calls)
  stageA(0, 0, 0, 0); stageA(0, 0, 0, 1); stageB(0, 0, 0);
  stageA(0, 0, 1, 0); stageA(0, 0, 1, 1); stageB(0, 0, 1);
  stageA(1, 1, 0, 0); stageA(1, 1, 0, 1); stageB(1, 1, 0);
  asm volatile("s_waitcnt vmcnt(3)" ::: "memory");
  __builtin_amdgcn_sched_barrier(0);
  __builtin_amdgcn_s_barrier();

  bf16x8 af[2][2], bfr[4][2];

#define MMA_Q(MQ, NQ)                                                          \
  __builtin_amdgcn_s_setprio(1);                                               \
  _Pragma("unroll")                                                            \
  for (int i = 0; i < 2; ++i)                                                  \
    _Pragma("unroll")                                                          \
    for (int j = 0; j < 2; ++j)                                                \
      _Pragma("unroll")                                                        \
      for (int ks = 0; ks < 2; ++ks)                                           \
        acc[(MQ)*2 + i][(NQ)*2 + j] = __builtin_amdgcn_mfma_f32_16x16x32_bf16( \
            af[i][ks], bfr[(NQ)*2 + j][ks], acc[(MQ)*2 + i][(NQ)*2 + j], 0, 0, 0); \
  __builtin_amdgcn_s_setprio(0);

  const int nt = 32;  // K=2048 / 64
  for (int c = 0; c < nt; ++c) {
    const int X = c & 1;
    const bool s1 = (c + 1 < nt), s2 = (c + 2 < nt);
    // ---- Phase 0: (m0,n0); stage tile c+1 A-mq1 -> other buf
    af[0][0] = ldA(X, 0, 0); af[0][1] = ldA(X, 0, 1);
    af[1][0] = ldA(X, 1, 0); af[1][1] = ldA(X, 1, 1);
    bfr[0][0] = ldB(X, 0, 0); bfr[0][1] = ldB(X, 0, 1);
    bfr[1][0] = ldB(X, 1, 0); bfr[1][1] = ldB(X, 1, 1);
    if (s1) { stageA(X ^ 1, c + 1, 1, 0); stageA(X ^ 1, c + 1, 1, 1); }
    MMA_Q(0, 0);
    __builtin_amdgcn_s_barrier();
    // ---- Phase 1: (m0,n1); stage tile c+1 B-nq1 -> other buf
    bfr[2][0] = ldB(X, 2, 0); bfr[2][1] = ldB(X, 2, 1);
    bfr[3][0] = ldB(X, 3, 0); bfr[3][1] = ldB(X, 3, 1);
    if (s1) stageB(X ^ 1, c + 1, 1);
    MMA_Q(0, 1);
    __builtin_amdgcn_s_barrier();
    // ---- Phase 2: (m1,n0); stage tile c+2 A-mq0 -> this buf (rows died after Ph1)
    af[0][0] = ldA(X, 2, 0); af[0][1] = ldA(X, 2, 1);
    af[1][0] = ldA(X, 3, 0); af[1][1] = ldA(X, 3, 1);
    if (s2) { stageA(X, c + 2, 0, 0); stageA(X, c + 2, 0, 1); }
    MMA_Q(1, 0);
    __builtin_amdgcn_s_barrier();
    // ---- Phase 3: (m1,n1); stage tile c+2 B-nq0 -> this buf (rows died after Ph2)
    if (s2) stageB(X, c + 2, 0);
    MMA_Q(1, 1);
    if (s2) asm volatile("s_waitcnt vmcnt(3)" ::: "memory");
    else    asm volatile("s_waitcnt vmcnt(0)" ::: "memory");
    __builtin_amdgcn_sched_barrier(0);
    __builtin_amdgcn_s_barrier();
  }
#undef MMA_Q

  // epilogue
#pragma unroll
  for (int mf = 0; mf < 4; ++mf) {
    const int irow = arow0 + wm * 64 + mf * 16 + g * 4;
#pragma unroll
    for (int nf = 0; nf < 4; ++nf) {
      const int jcol = bcol0 + wn * 64 + nf * 16 + r16;
      if (MODE == 1) {
        const float bval = b0[jcol];
#pragma unroll
        for (int rr = 0; rr < 4; ++rr)
          fo[(size_t)(irow + rr) * 2048 + jcol] = acc[mf][nf][rr] + bval;
      } else {
        const int which = bj >> 4;  // 0=Q 1=K 2=V
        const int jl = jcol & 2047;
        const int hh = jl >> 6, d = jl & 63;
        const float bval = (which == 0) ? b0[jl] : (which == 1) ? b1[jl] : b2[jl];
        const float osc = (which == 0) ? qscale : 1.0f;
        unsigned short* outp = (which == 0) ? o0 : (which == 1) ? o1 : o2;
#pragma unroll
        for (int rr = 0; rr < 4; ++rr) {
          const float val = (acc[mf][nf][rr] + bval) * osc;
          const int i = irow + rr;
          const int b = i >> 11, s = i & 2047;
          size_t off;
          if (which < 2) off = (((size_t)(b * NHEADS + hh)) * SEQ + s) * HDIM + d;
          else           off = (((size_t)(b * NHEADS + hh)) * HDIM + d) * SEQ + s;
          outp[off] = f2bf(val);
        }
      }
    }
  }
}

// ---------------- causal flash attention, swapped 32x32 QK^T, in-register softmax ----------------
// One q-tile (128 rows) per block; grid 1024 -> 4 blocks/CU (16 waves/CU resident).
// bh = blk & 63 (64 = 0 mod 8 -> all q-tiles of a bh on one XCD; 8 bh x 512KB K/V = 4MB L2).
// q-tile permutation: every stride-4 sample sums to 30 -> each CU's 4 resident blocks
// carry exactly 68 tile-units (perfect static balance).
__global__ __launch_bounds__(256, 2)
void attn_kernel(const unsigned short* __restrict__ Q,
                 const unsigned short* __restrict__ K,
                 const unsigned short* __restrict__ Vt,
                 unsigned short* __restrict__ O) {
  __shared__ unsigned short K_lds[2][64 * 72];
  __shared__ unsigned short V_lds[2][64 * 72];
  __shared__ __align__(16) float abuf[4][32];
  __shared__ __align__(16) float lbuf[4][32];
  const int tid = threadIdx.x;
  const int w = tid >> 6, l = tid & 63;
  const int q5 = l & 31, hi = l >> 5;
  const int bh = blockIdx.x & 63;
  const int qt = (int)((0xD5912A6EC4803B7FULL >> ((blockIdx.x >> 6) * 4)) & 0xFULL);
  const unsigned short* Qh = Q + (size_t)bh * SEQ * HDIM;
  const unsigned short* Kh = K + (size_t)bh * SEQ * HDIM;
  const unsigned short* Vh = Vt + (size_t)bh * HDIM * SEQ;
  const int bq = bh >> 5, hh = bh & 31;
  const int srow = tid >> 3;
  const int scol = (tid & 7) * 8;

  const int wrow0 = qt * 128 + w * 32;
  const int wrow_max = wrow0 + 31;
  const int n_tiles = 2 * qt + 2;
  const int qrow = wrow0 + q5;

  bf16x8 qf[4];
#pragma unroll
  for (int ks = 0; ks < 4; ++ks)
    qf[ks] = *(const bf16x8*)(Qh + (size_t)qrow * HDIM + ks * 16 + hi * 8);

  f32x16 oacc[2];
#pragma unroll
  for (int df = 0; df < 2; ++df)
#pragma unroll
    for (int r = 0; r < 16; ++r) oacc[df][r] = 0.f;
  float m_run = -3.0e38f, l_run = 0.f;

  bf16x8 kreg[2], vreg[2];
#pragma unroll
  for (int j = 0; j < 2; ++j) {
    const int rr = j * 32 + srow;
    kreg[j] = *(const bf16x8*)(Kh + (size_t)rr * HDIM + scol);
    vreg[j] = *(const bf16x8*)(Vh + (size_t)rr * SEQ + scol);
  }
#pragma unroll
  for (int j = 0; j < 2; ++j) {
    const int rr = j * 32 + srow;
    *(bf16x8*)(K_lds[0] + rr * 72 + scol) = kreg[j];
    *(bf16x8*)(V_lds[0] + rr * 72 + scol) = vreg[j];
  }

  for (int t = 0; t < n_tiles; ++t) {
    const int cur = t & 1;
    const bool not_last = (t + 1 < n_tiles);
    if (not_last) {
#pragma unroll
      for (int j = 0; j < 2; ++j) {
        const int rr = j * 32 + srow;
        kreg[j] = *(const bf16x8*)(Kh + (size_t)((t + 1) * 64 + rr) * HDIM + scol);
        vreg[j] = *(const bf16x8*)(Vh + (size_t)rr * SEQ + (t + 1) * 64 + scol);
      }
    }
    __syncthreads();

    if (t * 64 <= wrow_max) {
      f32x16 skf[2];
#pragma unroll
      for (int kf = 0; kf < 2; ++kf)
#pragma unroll
        for (int r = 0; r < 16; ++r) skf[kf][r] = 0.f;
      __builtin_amdgcn_s_setprio(1);
#pragma unroll
      for (int kf = 0; kf < 2; ++kf)
#pragma unroll
        for (int ks = 0; ks < 4; ++ks) {
          bf16x8 ak = *(const bf16x8*)(K_lds[cur] + (kf * 32 + q5) * 72 + ks * 16 + hi * 8);
          skf[kf] = __builtin_amdgcn_mfma_f32_32x32x16_bf16(ak, qf[ks], skf[kf], 0, 0, 0);
        }
      __builtin_amdgcn_s_setprio(0);

      const bool need_mask = (t * 64 + 63 > wrow0);
      if (need_mask) {
#pragma unroll
        for (int kf = 0; kf < 2; ++kf)
#pragma unroll
          for (int r = 0; r < 16; ++r) {
            const int key = t * 64 + kf * 32 + (r & 3) + 8 * (r >> 2) + 4 * hi;
            if (key > qrow) skf[kf][r] = -3.0e38f;
          }
      }

      float mx = -3.0e38f;
#pragma unroll
      for (int kf = 0; kf < 2; ++kf)
#pragma unroll
        for (int r = 0; r < 16; ++r) mx = fmaxf(mx, skf[kf][r]);
      mx = fmaxf(mx, __shfl_xor(mx, 32));

      if (__any(mx > m_run + 8.0f)) {
        const float mnew = fmaxf(m_run, mx);
        const float alpha = exp2f(m_run - mnew);
        m_run = mnew;
        l_run *= alpha;
        if (l < 32) abuf[w][l] = alpha;
        f32x4 av[4];
#pragma unroll
        for (int k = 0; k < 4; ++k)
          av[k] = *(const f32x4*)&abuf[w][8 * k + 4 * hi];
#pragma unroll
        for (int df = 0; df < 2; ++df)
#pragma unroll
          for (int r = 0; r < 16; ++r) oacc[df][r] *= av[r >> 2][r & 3];
      }

      unsigned int pkA[8], pkB[8];
      float psum = 0.f;
#pragma unroll
      for (int kf = 0; kf < 2; ++kf)
#pragma unroll
        for (int rr = 0; rr < 4; ++rr) {
          unsigned int pb[4];
#pragma unroll
          for (int j = 0; j < 4; ++j) {
            const float p = exp2f(skf[kf][rr * 4 + j] - m_run);
            psum += p;
            union { float f; unsigned int u; } c; c.f = p;
            pb[j] = c.u + 0x8000u;
          }
          pkA[kf * 4 + rr] = __builtin_amdgcn_perm(pb[1], pb[0], 0x07060302);
          pkB[kf * 4 + rr] = __builtin_amdgcn_perm(pb[3], pb[2], 0x07060302);
        }
      psum += __shfl_xor(psum, 32);
      l_run += psum;

      __builtin_amdgcn_s_setprio(1);
#pragma unroll
      for (int ks = 0; ks < 4; ++ks) {
        u32x2 ra = __builtin_amdgcn_permlane32_swap(pkA[2 * ks], pkA[2 * ks + 1], false, false);
        u32x2 rb = __builtin_amdgcn_permlane32_swap(pkB[2 * ks], pkB[2 * ks + 1], false, false);
        union { unsigned int u[4]; bf16x8 v; } pa;
        pa.u[0] = ra.x; pa.u[1] = rb.x; pa.u[2] = ra.y; pa.u[3] = rb.y;
#pragma unroll
        for (int df = 0; df < 2; ++df) {
          bf16x8 vf = *(const bf16x8*)(V_lds[cur] + (df * 32 + q5) * 72 + ks * 16 + hi * 8);
          oacc[df] = __builtin_amdgcn_mfma_f32_32x32x16_bf16(pa.v, vf, oacc[df], 0, 0, 0);
        }
      }
      __builtin_amdgcn_s_setprio(0);
    }

    if (not_last) {
#pragma unroll
      for (int j = 0; j < 2; ++j) {
        const int rr = j * 32 + srow;
        *(bf16x8*)(K_lds[cur ^ 1] + rr * 72 + scol) = kreg[j];
        *(bf16x8*)(V_lds[cur ^ 1] + rr * 72 + scol) = vreg[j];
      }
    }
  }

  if (l < 32) lbuf[w][l] = l_run;
  f32x4 lv[4];
#pragma unroll
  for (int k = 0; k < 4; ++k)
    lv[k] = *(const f32x4*)&lbuf[w][8 * k + 4 * hi];
#pragma unroll
  for (int df = 0; df < 2; ++df) {
    const int d = df * 32 + q5;
#pragma unroll
    for (int r = 0; r < 16; ++r) {
      const int s = wrow0 + (r & 3) + 8 * (r >> 2) + 4 * hi;
      const float inv = __builtin_amdgcn_rcpf(lv[r >> 2][r & 3]);
      O[((size_t)(bq * SEQ + s)) * EMBED + hh * HDIM + d] = f2bf(oacc[df][r] * inv);
    }
  }
}

extern "C" void kernel_launch(void* const* d_in, const int* in_sizes, int n_in,
                              void* d_out, int out_size, void* d_ws, size_t ws_size,
                              hipStream_t stream) {
  const float* h  = (const float*)d_in[0];
  const float* Wq = (const float*)d_in[1];
  const float* bq = (const float*)d_in[2];
  const float* Wk = (const float*)d_in[3];
  const float* bk = (const float*)d_in[4];
  const float* Wv = (const float*)d_in[5];
  const float* bv = (const float*)d_in[6];
  const float* Wo = (const float*)d_in[7];
  const float* bo = (const float*)d_in[8];

  if (ws_size < (size_t)117440512) return;

  unsigned short* ws = (unsigned short*)d_ws;
  unsigned short* hb = ws;                    // [4096,2048] bf16
  unsigned short* wqb = ws + 8388608;         // [6144,2048] contiguous QKV weights
  unsigned short* wob = ws + 20971520;
  unsigned short* Qw  = ws + 25165824;        // [B,H,S,D] (pre-scaled)
  unsigned short* Kw  = ws + 33554432;        // [B,H,S,D]
  unsigned short* Vw  = ws + 41943040;        // [B,H,D,S]
  unsigned short* Ow  = ws + 50331648;        // [B,S,E]

  cvt_all<<<2048, 256, 0, stream>>>(h, Wq, Wk, Wv, Wo, ws);

  const float qscale = ATT_SCALE * LOG2E;
  gemm8<0, 48><<<768, 512, 0, stream>>>(hb, wqb, bq, bk, bv, Qw, Kw, Vw, nullptr, qscale);

  attn_kernel<<<1024, 256, 0, stream>>>(Qw, Kw, Vw, Ow);

  gemm8<1, 16><<<256, 512, 0, stream>>>(Ow, wob, bo, bo, bo, nullptr, nullptr, nullptr,
                                        (float*)d_out, 1.0f);
}

// Round 14
// 245.923 us; speedup vs baseline: 1.0643x; 1.0643x over previous
//
#include <hip/hip_runtime.h>
#include <hip/hip_bf16.h>
#include <stdint.h>

#define EMBED 2048
#define NHEADS 32
#define HDIM 64
#define BATCH 2
#define SEQ 2048
#define ATT_SCALE 0.125f
#define LOG2E 1.4426950408889634f

typedef __attribute__((ext_vector_type(8))) short bf16x8;
typedef __attribute__((ext_vector_type(4))) float f32x4;
typedef __attribute__((ext_vector_type(16))) float f32x16;
typedef __attribute__((ext_vector_type(4))) unsigned short u16x4;
typedef __attribute__((ext_vector_type(2))) unsigned int u32x2;

static __device__ __forceinline__ unsigned short f2bf(float f) {
  union { float f; uint32_t u; } v; v.f = f;
  uint32_t r = v.u + 0x7fffu + ((v.u >> 16) & 1u);
  return (unsigned short)(r >> 16);
}

static __device__ __forceinline__ void gload_lds16(const unsigned short* g, unsigned short* l) {
  __builtin_amdgcn_global_load_lds(
      (const __attribute__((address_space(1))) unsigned int*)g,
      (__attribute__((address_space(3))) unsigned int*)l, 16, 0, 0);
}

// ---------------- fp32 -> bf16 cast, all 5 tensors fused ----------------
__global__ void cvt_all(const float* __restrict__ h,
                        const float* __restrict__ Wq, const float* __restrict__ Wk,
                        const float* __restrict__ Wv, const float* __restrict__ Wo,
                        unsigned short* __restrict__ out) {
  const int n4 = 6291456;
  int idx = blockIdx.x * blockDim.x + threadIdx.x;
  int stride = gridDim.x * blockDim.x;
  for (int i = idx; i < n4; i += stride) {
    const float* src; int off;
    if (i < 2097152)      { src = h;  off = i; }
    else if (i < 3145728) { src = Wq; off = i - 2097152; }
    else if (i < 4194304) { src = Wk; off = i - 3145728; }
    else if (i < 5242880) { src = Wv; off = i - 4194304; }
    else                  { src = Wo; off = i - 5242880; }
    float4 v = ((const float4*)src)[off];
    u16x4 o;
    o.x = f2bf(v.x); o.y = f2bf(v.y); o.z = f2bf(v.z); o.w = f2bf(v.w);
    ((u16x4*)out)[i] = o;
  }
}

// ---------------- 8-phase pipelined GEMM (R6 measured-best, byte-identical) ----------------
// BM=256, BN=128, BK=64, 512 threads = 8 waves (4M x 2N), wave tile 64x64.
// MODE 0: QKV fused epilogue (bf16 scatter); MODE 1: fp32 row-major + bias.
template<int MODE, int NBJ>
__global__ __launch_bounds__(512, 2)
void gemm8(const unsigned short* __restrict__ A,
           const unsigned short* __restrict__ W,
           const float* __restrict__ b0, const float* __restrict__ b1,
           const float* __restrict__ b2,
           unsigned short* __restrict__ o0, unsigned short* __restrict__ o1,
           unsigned short* __restrict__ o2,
           float* __restrict__ fo, float qscale) {
  __shared__ unsigned short lds[2][24576];   // per buf: A [256][64] @0, B [128][64] @16384
  const int tid = threadIdx.x;
  const int w = tid >> 6, l = tid & 63;
  const int wm = w >> 1, wn = w & 1;
  const int r16 = l & 15, g = l >> 4;
  // R6 XCD swizzle (measured best): each XCD gets a contiguous swz chunk
  const int nblk = 16 * NBJ;
  const int swz = (blockIdx.x & 7) * (nblk >> 3) + (blockIdx.x >> 3);
  const int bi = swz / NBJ, bj = swz % NBJ;
  const int arow0 = bi * 256, bcol0 = bj * 128;

  f32x4 acc[4][4];
#pragma unroll
  for (int i = 0; i < 4; ++i)
#pragma unroll
    for (int j = 0; j < 4; ++j) acc[i][j] = (f32x4){0.f, 0.f, 0.f, 0.f};

  const int lrow = l >> 3;               // 0..7 within a wave's 8-row chunk
  const int gcu = ((l & 7) ^ lrow) * 8;  // pre-swizzled global column (elements)

  auto stageA = [&](int buf, int t, int mq, int call) {
    const int m = call * 8 + w;
    const int row0 = mq * 32 + (m >> 2) * 64 + (m & 3) * 8;
    gload_lds16(A + (size_t)(arow0 + row0 + lrow) * 2048 + t * 64 + gcu,
                &lds[buf][row0 * 64]);
  };
  auto stageB = [&](int buf, int t, int nq) {
    const int row0 = nq * 32 + (w >> 2) * 64 + (w & 3) * 8;
    gload_lds16(W + (size_t)(bcol0 + row0 + lrow) * 2048 + t * 64 + gcu,
                &lds[buf][16384 + row0 * 64]);
  };
  auto ldA = [&](int buf, int mf, int ks) -> bf16x8 {
    const int row = wm * 64 + mf * 16 + r16;
    const int u = (ks * 4 + g) ^ (r16 & 7);
    return *(const bf16x8*)&lds[buf][row * 64 + u * 8];
  };
  auto ldB = [&](int buf, int nf, int ks) -> bf16x8 {
    const int row = wn * 64 + nf * 16 + r16;
    const int u = (ks * 4 + g) ^ (r16 & 7);
    return *(const bf16x8*)&lds[buf][16384 + row * 64 + u * 8];
  };

  // prologue: tile 0 full -> buf0 (6 calls, oldest), tile 1 early chunks -> buf1 (3 calls)
  stageA(0, 0, 0, 0); stageA(0, 0, 0, 1); stageB(0, 0, 0);
  stageA(0, 0, 1, 0); stageA(0, 0, 1, 1); stageB(0, 0, 1);
  stageA(1, 1, 0, 0); stageA(1, 1, 0, 1); stageB(1, 1, 0);
  asm volatile("s_waitcnt vmcnt(3)" ::: "memory");
  __builtin_amdgcn_sched_barrier(0);
  __builtin_amdgcn_s_barrier();

  bf16x8 af[2][2], bfr[4][2];

#define MMA_Q(MQ, NQ)                                                          \
  __builtin_amdgcn_s_setprio(1);                                               \
  _Pragma("unroll")                                                            \
  for (int i = 0; i < 2; ++i)                                                  \
    _Pragma("unroll")                                                          \
    for (int j = 0; j < 2; ++j)                                                \
      _Pragma("unroll")                                                        \
      for (int ks = 0; ks < 2; ++ks)                                           \
        acc[(MQ)*2 + i][(NQ)*2 + j] = __builtin_amdgcn_mfma_f32_16x16x32_bf16( \
            af[i][ks], bfr[(NQ)*2 + j][ks], acc[(MQ)*2 + i][(NQ)*2 + j], 0, 0, 0); \
  __builtin_amdgcn_s_setprio(0);

  const int nt = 32;  // K=2048 / 64
  for (int c = 0; c < nt; ++c) {
    const int X = c & 1;
    const bool s1 = (c + 1 < nt), s2 = (c + 2 < nt);
    // ---- Phase 0: (m0,n0); stage tile c+1 A-mq1 -> other buf
    af[0][0] = ldA(X, 0, 0); af[0][1] = ldA(X, 0, 1);
    af[1][0] = ldA(X, 1, 0); af[1][1] = ldA(X, 1, 1);
    bfr[0][0] = ldB(X, 0, 0); bfr[0][1] = ldB(X, 0, 1);
    bfr[1][0] = ldB(X, 1, 0); bfr[1][1] = ldB(X, 1, 1);
    if (s1) { stageA(X ^ 1, c + 1, 1, 0); stageA(X ^ 1, c + 1, 1, 1); }
    MMA_Q(0, 0);
    __builtin_amdgcn_s_barrier();
    // ---- Phase 1: (m0,n1); stage tile c+1 B-nq1 -> other buf
    bfr[2][0] = ldB(X, 2, 0); bfr[2][1] = ldB(X, 2, 1);
    bfr[3][0] = ldB(X, 3, 0); bfr[3][1] = ldB(X, 3, 1);
    if (s1) stageB(X ^ 1, c + 1, 1);
    MMA_Q(0, 1);
    __builtin_amdgcn_s_barrier();
    // ---- Phase 2: (m1,n0); stage tile c+2 A-mq0 -> this buf (rows died after Ph1)
    af[0][0] = ldA(X, 2, 0); af[0][1] = ldA(X, 2, 1);
    af[1][0] = ldA(X, 3, 0); af[1][1] = ldA(X, 3, 1);
    if (s2) { stageA(X, c + 2, 0, 0); stageA(X, c + 2, 0, 1); }
    MMA_Q(1, 0);
    __builtin_amdgcn_s_barrier();
    // ---- Phase 3: (m1,n1); stage tile c+2 B-nq0 -> this buf (rows died after Ph2)
    if (s2) stageB(X, c + 2, 0);
    MMA_Q(1, 1);
    if (s2) asm volatile("s_waitcnt vmcnt(3)" ::: "memory");
    else    asm volatile("s_waitcnt vmcnt(0)" ::: "memory");
    __builtin_amdgcn_sched_barrier(0);
    __builtin_amdgcn_s_barrier();
  }
#undef MMA_Q

  // epilogue
#pragma unroll
  for (int mf = 0; mf < 4; ++mf) {
    const int irow = arow0 + wm * 64 + mf * 16 + g * 4;
#pragma unroll
    for (int nf = 0; nf < 4; ++nf) {
      const int jcol = bcol0 + wn * 64 + nf * 16 + r16;
      if (MODE == 1) {
        const float bval = b0[jcol];
#pragma unroll
        for (int rr = 0; rr < 4; ++rr)
          fo[(size_t)(irow + rr) * 2048 + jcol] = acc[mf][nf][rr] + bval;
      } else {
        const int which = bj >> 4;  // 0=Q 1=K 2=V
        const int jl = jcol & 2047;
        const int hh = jl >> 6, d = jl & 63;
        const float bval = (which == 0) ? b0[jl] : (which == 1) ? b1[jl] : b2[jl];
        const float osc = (which == 0) ? qscale : 1.0f;
        unsigned short* outp = (which == 0) ? o0 : (which == 1) ? o1 : o2;
#pragma unroll
        for (int rr = 0; rr < 4; ++rr) {
          const float val = (acc[mf][nf][rr] + bval) * osc;
          const int i = irow + rr;
          const int b = i >> 11, s = i & 2047;
          size_t off;
          if (which < 2) off = (((size_t)(b * NHEADS + hh)) * SEQ + s) * HDIM + d;
          else           off = (((size_t)(b * NHEADS + hh)) * HDIM + d) * SEQ + s;
          outp[off] = f2bf(val);
        }
      }
    }
  }
}

// ---------------- causal flash attention, swapped 32x32 QK^T, in-register softmax ----------------
// Block = 4 waves, q-tiles {pair, 15-pair} of one (b,h): uniform 34 tile-units/block (R6).
__global__ __launch_bounds__(256, 2)
void attn_kernel(const unsigned short* __restrict__ Q,
                 const unsigned short* __restrict__ K,
                 const unsigned short* __restrict__ Vt,
                 unsigned short* __restrict__ O) {
  __shared__ unsigned short K_lds[2][64 * 72];
  __shared__ unsigned short V_lds[2][64 * 72];
  __shared__ __align__(16) float abuf[4][32];
  __shared__ __align__(16) float lbuf[4][32];
  const int tid = threadIdx.x;
  const int w = tid >> 6, l = tid & 63;
  const int q5 = l & 31, hi = l >> 5;
  const int bid = ((blockIdx.x & 7) << 6) | (blockIdx.x >> 3);
  const int pair = bid & 7;
  const int bh = bid >> 3;
  const unsigned short* Qh = Q + (size_t)bh * SEQ * HDIM;
  const unsigned short* Kh = K + (size_t)bh * SEQ * HDIM;
  const unsigned short* Vh = Vt + (size_t)bh * HDIM * SEQ;
  const int bq = bh >> 5, hh = bh & 31;
  const int srow = tid >> 3;
  const int scol = (tid & 7) * 8;

  for (int half = 0; half < 2; ++half) {
    const int qt = half ? (15 - pair) : pair;
    const int wrow0 = qt * 128 + w * 32;
    const int wrow_max = wrow0 + 31;
    const int n_tiles = 2 * qt + 2;
    const int qrow = wrow0 + q5;

    bf16x8 qf[4];
#pragma unroll
    for (int ks = 0; ks < 4; ++ks)
      qf[ks] = *(const bf16x8*)(Qh + (size_t)qrow * HDIM + ks * 16 + hi * 8);

    f32x16 oacc[2];
#pragma unroll
    for (int df = 0; df < 2; ++df)
#pragma unroll
      for (int r = 0; r < 16; ++r) oacc[df][r] = 0.f;
    float m_run = -3.0e38f, l_run = 0.f;

    bf16x8 kreg[2], vreg[2];
#pragma unroll
    for (int j = 0; j < 2; ++j) {
      const int rr = j * 32 + srow;
      kreg[j] = *(const bf16x8*)(Kh + (size_t)rr * HDIM + scol);
      vreg[j] = *(const bf16x8*)(Vh + (size_t)rr * SEQ + scol);
    }
    __syncthreads();
#pragma unroll
    for (int j = 0; j < 2; ++j) {
      const int rr = j * 32 + srow;
      *(bf16x8*)(K_lds[0] + rr * 72 + scol) = kreg[j];
      *(bf16x8*)(V_lds[0] + rr * 72 + scol) = vreg[j];
    }

    for (int t = 0; t < n_tiles; ++t) {
      const int cur = t & 1;
      const bool not_last = (t + 1 < n_tiles);
      if (not_last) {
#pragma unroll
        for (int j = 0; j < 2; ++j) {
          const int rr = j * 32 + srow;
          kreg[j] = *(const bf16x8*)(Kh + (size_t)((t + 1) * 64 + rr) * HDIM + scol);
          vreg[j] = *(const bf16x8*)(Vh + (size_t)rr * SEQ + (t + 1) * 64 + scol);
        }
      }
      __syncthreads();

      if (t * 64 <= wrow_max) {
        f32x16 skf[2];
#pragma unroll
        for (int kf = 0; kf < 2; ++kf)
#pragma unroll
          for (int r = 0; r < 16; ++r) skf[kf][r] = 0.f;
        __builtin_amdgcn_s_setprio(1);
#pragma unroll
        for (int kf = 0; kf < 2; ++kf)
#pragma unroll
          for (int ks = 0; ks < 4; ++ks) {
            bf16x8 ak = *(const bf16x8*)(K_lds[cur] + (kf * 32 + q5) * 72 + ks * 16 + hi * 8);
            skf[kf] = __builtin_amdgcn_mfma_f32_32x32x16_bf16(ak, qf[ks], skf[kf], 0, 0, 0);
          }
        __builtin_amdgcn_s_setprio(0);

        const bool need_mask = (t * 64 + 63 > wrow0);
        if (need_mask) {
#pragma unroll
          for (int kf = 0; kf < 2; ++kf)
#pragma unroll
            for (int r = 0; r < 16; ++r) {
              const int key = t * 64 + kf * 32 + (r & 3) + 8 * (r >> 2) + 4 * hi;
              if (key > qrow) skf[kf][r] = -3.0e38f;
            }
        }

        float mx = -3.0e38f;
#pragma unroll
        for (int kf = 0; kf < 2; ++kf)
#pragma unroll
          for (int r = 0; r < 16; ++r) mx = fmaxf(mx, skf[kf][r]);
        mx = fmaxf(mx, __shfl_xor(mx, 32));

        if (__any(mx > m_run + 8.0f)) {
          const float mnew = fmaxf(m_run, mx);
          const float alpha = exp2f(m_run - mnew);
          m_run = mnew;
          l_run *= alpha;
          if (l < 32) abuf[w][l] = alpha;
          f32x4 av[4];
#pragma unroll
          for (int k = 0; k < 4; ++k)
            av[k] = *(const f32x4*)&abuf[w][8 * k + 4 * hi];
#pragma unroll
          for (int df = 0; df < 2; ++df)
#pragma unroll
            for (int r = 0; r < 16; ++r) oacc[df][r] *= av[r >> 2][r & 3];
        }

        unsigned int pkA[8], pkB[8];
        float psum = 0.f;
#pragma unroll
        for (int kf = 0; kf < 2; ++kf)
#pragma unroll
          for (int rr = 0; rr < 4; ++rr) {
            unsigned int pb[4];
#pragma unroll
            for (int j = 0; j < 4; ++j) {
              const float p = exp2f(skf[kf][rr * 4 + j] - m_run);
              psum += p;
              union { float f; unsigned int u; } c; c.f = p;
              pb[j] = c.u + 0x8000u;
            }
            pkA[kf * 4 + rr] = __builtin_amdgcn_perm(pb[1], pb[0], 0x07060302);
            pkB[kf * 4 + rr] = __builtin_amdgcn_perm(pb[3], pb[2], 0x07060302);
          }
        psum += __shfl_xor(psum, 32);
        l_run += psum;

        __builtin_amdgcn_s_setprio(1);
#pragma unroll
        for (int ks = 0; ks < 4; ++ks) {
          u32x2 ra = __builtin_amdgcn_permlane32_swap(pkA[2 * ks], pkA[2 * ks + 1], false, false);
          u32x2 rb = __builtin_amdgcn_permlane32_swap(pkB[2 * ks], pkB[2 * ks + 1], false, false);
          union { unsigned int u[4]; bf16x8 v; } pa;
          pa.u[0] = ra.x; pa.u[1] = rb.x; pa.u[2] = ra.y; pa.u[3] = rb.y;
#pragma unroll
          for (int df = 0; df < 2; ++df) {
            bf16x8 vf = *(const bf16x8*)(V_lds[cur] + (df * 32 + q5) * 72 + ks * 16 + hi * 8);
            oacc[df] = __builtin_amdgcn_mfma_f32_32x32x16_bf16(pa.v, vf, oacc[df], 0, 0, 0);
          }
        }
        __builtin_amdgcn_s_setprio(0);
      }

      if (not_last) {
#pragma unroll
        for (int j = 0; j < 2; ++j) {
          const int rr = j * 32 + srow;
          *(bf16x8*)(K_lds[cur ^ 1] + rr * 72 + scol) = kreg[j];
          *(bf16x8*)(V_lds[cur ^ 1] + rr * 72 + scol) = vreg[j];
        }
      }
    }

    if (l < 32) lbuf[w][l] = l_run;
    f32x4 lv[4];
#pragma unroll
    for (int k = 0; k < 4; ++k)
      lv[k] = *(const f32x4*)&lbuf[w][8 * k + 4 * hi];
#pragma unroll
    for (int df = 0; df < 2; ++df) {
      const int d = df * 32 + q5;
#pragma unroll
      for (int r = 0; r < 16; ++r) {
        const int s = wrow0 + (r & 3) + 8 * (r >> 2) + 4 * hi;
        const float inv = __builtin_amdgcn_rcpf(lv[r >> 2][r & 3]);
        O[((size_t)(bq * SEQ + s)) * EMBED + hh * HDIM + d] = f2bf(oacc[df][r] * inv);
      }
    }
  }
}

extern "C" void kernel_launch(void* const* d_in, const int* in_sizes, int n_in,
                              void* d_out, int out_size, void* d_ws, size_t ws_size,
                              hipStream_t stream) {
  const float* h  = (const float*)d_in[0];
  const float* Wq = (const float*)d_in[1];
  const float* bq = (const float*)d_in[2];
  const float* Wk = (const float*)d_in[3];
  const float* bk = (const float*)d_in[4];
  const float* Wv = (const float*)d_in[5];
  const float* bv = (const float*)d_in[6];
  const float* Wo = (const float*)d_in[7];
  const float* bo = (const float*)d_in[8];

  if (ws_size < (size_t)117440512) return;

  unsigned short* ws = (unsigned short*)d_ws;
  unsigned short* hb = ws;                    // [4096,2048] bf16
  unsigned short* wqb = ws + 8388608;         // [6144,2048] contiguous QKV weights
  unsigned short* wob = ws + 20971520;
  unsigned short* Qw  = ws + 25165824;        // [B,H,S,D] (pre-scaled)
  unsigned short* Kw  = ws + 33554432;        // [B,H,S,D]
  unsigned short* Vw  = ws + 41943040;        // [B,H,D,S]
  unsigned short* Ow  = ws + 50331648;        // [B,S,E]

  cvt_all<<<2048, 256, 0, stream>>>(h, Wq, Wk, Wv, Wo, ws);

  const float qscale = ATT_SCALE * LOG2E;
  gemm8<0, 48><<<768, 512, 0, stream>>>(hb, wqb, bq, bk, bv, Qw, Kw, Vw, nullptr, qscale);

  attn_kernel<<<512, 256, 0, stream>>>(Qw, Kw, Vw, Ow);

  gemm8<1, 16><<<256, 512, 0, stream>>>(Ow, wob, bo, bo, bo, nullptr, nullptr, nullptr,
                                        (float*)d_out, 1.0f);
}